// Round 5
// baseline (870.480 us; speedup 1.0000x reference)
//
#include <hip/hip_runtime.h>
#include <hip/hip_bf16.h>
#include <math.h>

#define DIM 1024
#define BATCH 16384
#define NLAYER 6

typedef __bf16 bf16_t;
typedef __attribute__((ext_vector_type(8))) __bf16 bf16x8;
typedef __attribute__((ext_vector_type(4))) float f32x4;

__device__ __forceinline__ void gload16(const void* g, void* l) {
  __builtin_amdgcn_global_load_lds(
      (const __attribute__((address_space(1))) void*)g,
      (__attribute__((address_space(3))) void*)l, 16, 0, 0);
}

__device__ __forceinline__ float fast_tanh(float x) {
  x = fminf(9.f, fmaxf(-9.f, x));
  const float e = __expf(x + x);
  return (e - 1.f) * __builtin_amdgcn_rcpf(e + 1.f);
}

__device__ __forceinline__ float bf2f(unsigned short u) {
  return __uint_as_float(((unsigned int)u) << 16);
}

__device__ __forceinline__ unsigned short f2bf(float v) {
  union { bf16_t b; unsigned short u; } t;
  t.b = (bf16_t)v;
  return t.u;
}

// ---------------------------------------------------------------------------
// GEMM: C[m,n] = sum_k A[m,k] * W[n,k]
// MODE 0: Tb = bf16( fast_tanh(scale[m]*C + b1[n]) )
// MODE 1: hb[m,n] = cf.w*hb_old + C + b2[n] + cf.x*e[n] + cf.y*c[n] + cf.z*n[n]
// MODE 2: like MODE 1 but writes fp32 outF only (final layer)
// K-loop: 128x128 tile, BK=64, 4 waves, XOR-swizzled LDS (0 conflicts).
// OPERAND SWAP (R5): W is the MFMA A-operand, h the B-operand, so
// D[n = quad*4+reg][m = lane&15]: each lane holds 4 CONSECUTIVE output
// columns of one row -> 8B/16B vectorized epilogue stores, no LDS round-trip
// (R4's staged epilogue regressed: barriers+scalar ds_writes+atomics).
// __launch_bounds__(256,4): VGPR<=128 -> 4 blocks/CU co-resident (R2 lesson).
// ---------------------------------------------------------------------------
template <int MODE>
__global__ __launch_bounds__(256, 4) void gemm_kernel(
    const bf16_t* __restrict__ A, const bf16_t* __restrict__ W,
    const float* __restrict__ bias, bf16_t* __restrict__ outB,
    float* __restrict__ outF, const f32x4* __restrict__ coef,
    const float* __restrict__ dirs, const float* __restrict__ scaleArr,
    const bf16_t* __restrict__ hbIn) {
  __shared__ __align__(16) bf16_t sA[128 * 64];
  __shared__ __align__(16) bf16_t sB[128 * 64];
  const int tid = threadIdx.x;
  const int w = tid >> 6;
  const int lane = tid & 63;
  const int bm = blockIdx.x * 128;
  const int bn = blockIdx.y * 128;
  const int wm = (w & 1) * 64;   // h-row (output row) range of this wave
  const int wn = (w >> 1) * 64;  // W-row (output col) range of this wave
  const int lm = lane & 15;
  const int lc = lane >> 4;  // 0..3

  f32x4 acc[4][4] = {};

  // staging: thread -> (row srow = tid>>3, phys chunk p = tid&7)
  // content at (row,p) = logical chunk p ^ (row&7).
  const int srow = tid >> 3;
  const int swz = ((tid & 7) ^ (srow & 7)) * 8;
  const bf16_t* gA = A + (size_t)(bm + srow) * DIM + swz;
  const bf16_t* gW = W + (size_t)(bn + srow) * DIM + swz;
  char* lA = (char*)sA + w * 1024;
  char* lB = (char*)sB + w * 1024;

  for (int kt = 0; kt < DIM; kt += 64) {
#pragma unroll
    for (int q = 0; q < 4; ++q) {
      gload16(gA + kt + (size_t)q * 32 * DIM, lA + q * 4096);
      gload16(gW + kt + (size_t)q * 32 * DIM, lB + q * 4096);
    }
    __syncthreads();
#pragma unroll
    for (int kh = 0; kh < 2; ++kh) {
      bf16x8 wF[4], hF[4];
      const int lgc = kh * 4 + lc;
      const int cswz = (lgc ^ (lm & 7)) << 4;
#pragma unroll
      for (int i = 0; i < 4; ++i) {
        const int rowW = wn + i * 16 + lm;
        wF[i] = *(const bf16x8*)((char*)sB + rowW * 128 + cswz);
      }
#pragma unroll
      for (int j = 0; j < 4; ++j) {
        const int rowH = wm + j * 16 + lm;
        hF[j] = *(const bf16x8*)((char*)sA + rowH * 128 + cswz);
      }
      // A-operand = W  -> D quad/reg side = output COLUMN (consecutive!)
      // B-operand = h  -> D lane side     = output ROW
#pragma unroll
      for (int i = 0; i < 4; ++i)
#pragma unroll
        for (int j = 0; j < 4; ++j)
          acc[i][j] = __builtin_amdgcn_mfma_f32_16x16x32_bf16(
              wF[i], hF[j], acc[i][j], 0, 0, 0);
    }
    __syncthreads();
  }

  // D layout: out_row m = bm+wm+j*16+lm ; out_col n = bn+wn+i*16+lc*4+r
  const int r0 = lc << 2;
#pragma unroll
  for (int j = 0; j < 4; ++j) {
    const int grow = bm + wm + j * 16 + lm;
    if constexpr (MODE == 0) {
      const float s = scaleArr[grow];
#pragma unroll
      for (int i = 0; i < 4; ++i) {
        const int gcol = bn + wn + i * 16 + r0;
        const float4 bv = *(const float4*)&bias[gcol];
        ushort4 o;
        o.x = f2bf(fast_tanh(s * acc[i][j][0] + bv.x));
        o.y = f2bf(fast_tanh(s * acc[i][j][1] + bv.y));
        o.z = f2bf(fast_tanh(s * acc[i][j][2] + bv.z));
        o.w = f2bf(fast_tanh(s * acc[i][j][3] + bv.w));
        *(ushort4*)&outB[(size_t)grow * DIM + gcol] = o;
      }
    } else {
      const f32x4 cf = coef[grow];
#pragma unroll
      for (int i = 0; i < 4; ++i) {
        const int gcol = bn + wn + i * 16 + r0;
        const float4 ev = *(const float4*)&dirs[gcol];
        const float4 cv = *(const float4*)&dirs[DIM + gcol];
        const float4 nv = *(const float4*)&dirs[2 * DIM + gcol];
        const float4 bv = *(const float4*)&bias[gcol];
        const ushort4 hp = *(const ushort4*)&hbIn[(size_t)grow * DIM + gcol];
        float v0 = acc[i][j][0] + bv.x + cf.x * ev.x + cf.y * cv.x +
                   cf.z * nv.x + cf.w * bf2f(hp.x);
        float v1 = acc[i][j][1] + bv.y + cf.x * ev.y + cf.y * cv.y +
                   cf.z * nv.y + cf.w * bf2f(hp.y);
        float v2 = acc[i][j][2] + bv.z + cf.x * ev.z + cf.y * cv.z +
                   cf.z * nv.z + cf.w * bf2f(hp.z);
        float v3 = acc[i][j][3] + bv.w + cf.x * ev.w + cf.y * cv.w +
                   cf.z * nv.w + cf.w * bf2f(hp.w);
        if constexpr (MODE == 1) {
          ushort4 o;
          o.x = f2bf(v0); o.y = f2bf(v1); o.z = f2bf(v2); o.w = f2bf(v3);
          *(ushort4*)&outB[(size_t)grow * DIM + gcol] = o;
        } else {
          float4 o;
          o.x = v0; o.y = v1; o.z = v2; o.w = v3;
          *(float4*)&outF[(size_t)grow * DIM + gcol] = o;
        }
      }
    }
  }
}

// ---------------------------------------------------------------------------
// Per-row stats: ||h||^2 and dots with e/c/n; produce
//   scaleArr[row] = clamp scale; coef[row] = {ce, cc, cn, scale*(1-ce-cc-cn)}
// IN_FP32: src fp32 (h0 or final outF). dstb != nullptr -> also cast to bf16.
// ---------------------------------------------------------------------------
template <int IN_FP32>
__global__ __launch_bounds__(256) void stats_kernel(
    const void* __restrict__ src, bf16_t* __restrict__ dstb,
    float* __restrict__ scaleArr, f32x4* __restrict__ coef,
    const float* __restrict__ dirs, int doClamp) {
  const int row = blockIdx.x;
  const int t = threadIdx.x;
  float4 v;
  if constexpr (IN_FP32) {
    v = ((const float4*)src)[(size_t)row * 256 + t];
  } else {
    const ushort4 u = ((const ushort4*)src)[(size_t)row * 256 + t];
    v.x = bf2f(u.x); v.y = bf2f(u.y); v.z = bf2f(u.z); v.w = bf2f(u.w);
  }
  const float4 e = ((const float4*)dirs)[t];
  const float4 c = ((const float4*)dirs)[t + 256];
  const float4 n = ((const float4*)dirs)[t + 512];
  float ss = v.x * v.x + v.y * v.y + v.z * v.z + v.w * v.w;
  float de = v.x * e.x + v.y * e.y + v.z * e.z + v.w * e.w;
  float dc = v.x * c.x + v.y * c.y + v.z * c.z + v.w * c.w;
  float dn = v.x * n.x + v.y * n.y + v.z * n.z + v.w * n.w;
#pragma unroll
  for (int off = 32; off; off >>= 1) {
    ss += __shfl_down(ss, off);
    de += __shfl_down(de, off);
    dc += __shfl_down(dc, off);
    dn += __shfl_down(dn, off);
  }
  __shared__ float red[4][4];
  const int w = t >> 6;
  if ((t & 63) == 0) {
    red[w][0] = ss; red[w][1] = de; red[w][2] = dc; red[w][3] = dn;
  }
  __syncthreads();
  if (dstb != nullptr) {
    union { bf16_t b[4]; uint2 u; } pk;
    pk.b[0] = (bf16_t)v.x; pk.b[1] = (bf16_t)v.y;
    pk.b[2] = (bf16_t)v.z; pk.b[3] = (bf16_t)v.w;
    ((uint2*)dstb)[(size_t)row * 256 + t] = pk.u;
  }
  if (t == 0) {
    float S = 0, E = 0, C = 0, N = 0;
#pragma unroll
    for (int i = 0; i < 4; ++i) {
      S += red[i][0]; E += red[i][1]; C += red[i][2]; N += red[i][3];
    }
    const float norm = sqrtf(S);
    float scale = 1.f;
    if (doClamp && norm > 10.f) scale = 10.f / (norm + 1e-8f);
    const float invn = 1.f / fmaxf(norm, 1e-12f);
    const float ae = E * invn;
    const float ac = C * invn;
    const float an = N * invn;
    const float nc = norm * scale;
    const float re = sqrtf(fmaxf(nc * nc - 2.f * nc * ae + 1.f, 0.f));
    const float rc = sqrtf(fmaxf(nc * nc - 2.f * nc * ac + 1.f, 0.f));
    const float rn = sqrtf(fmaxf(nc * nc - 2.f * nc * an + 1.f, 0.f));
    const float boundary = fminf(fmaxf(1.f - fabsf(ae - ac), 0.f), 1.f);
    f32x4 cf;
    cf.x = 0.1f * (1.f - ae) / fmaxf(re, 1e-12f);
    cf.y = 0.1f * (1.f - ac) / fmaxf(rc, 1e-12f);
    cf.z = (0.05f * (1.f - an) + 0.05f * boundary) / fmaxf(rn, 1e-12f);
    cf.w = scale * (1.f - cf.x - cf.y - cf.z);
    coef[row] = cf;
    scaleArr[row] = scale;
  }
}

__global__ __launch_bounds__(256) void finalize_kernel(
    float* __restrict__ outF, const float* __restrict__ scaleArr) {
  const int row = blockIdx.x;
  const int t = threadIdx.x;
  const float s = scaleArr[row];
  float4 v = ((float4*)outF)[(size_t)row * 256 + t];
  v.x *= s; v.y *= s; v.z *= s; v.w *= s;
  ((float4*)outF)[(size_t)row * 256 + t] = v;
}

__global__ __launch_bounds__(256) void prep_dirs(
    const float* __restrict__ ae, const float* __restrict__ ac,
    const float* __restrict__ an, float* __restrict__ dirs) {
  const int t = threadIdx.x;
  const float4 a = ((const float4*)ae)[t];
  const float4 b = ((const float4*)ac)[t];
  const float4 c = ((const float4*)an)[t];
  float sa = a.x * a.x + a.y * a.y + a.z * a.z + a.w * a.w;
  float sb = b.x * b.x + b.y * b.y + b.z * b.z + b.w * b.w;
  float sc = c.x * c.x + c.y * c.y + c.z * c.z + c.w * c.w;
#pragma unroll
  for (int off = 32; off; off >>= 1) {
    sa += __shfl_down(sa, off);
    sb += __shfl_down(sb, off);
    sc += __shfl_down(sc, off);
  }
  __shared__ float red[4][3];
  __shared__ float fin[3];
  const int w = t >> 6;
  if ((t & 63) == 0) { red[w][0] = sa; red[w][1] = sb; red[w][2] = sc; }
  __syncthreads();
  if (t == 0) {
    float x = 0, y = 0, z = 0;
#pragma unroll
    for (int i = 0; i < 4; ++i) { x += red[i][0]; y += red[i][1]; z += red[i][2]; }
    fin[0] = x; fin[1] = y; fin[2] = z;
  }
  __syncthreads();
  const float ia = 1.f / fmaxf(sqrtf(fin[0]), 1e-12f);
  const float ib = 1.f / fmaxf(sqrtf(fin[1]), 1e-12f);
  const float ic = 1.f / fmaxf(sqrtf(fin[2]), 1e-12f);
  float4 oa, ob, oc;
  oa.x = a.x * ia; oa.y = a.y * ia; oa.z = a.z * ia; oa.w = a.w * ia;
  ob.x = b.x * ib; ob.y = b.y * ib; ob.z = b.z * ib; ob.w = b.w * ib;
  oc.x = c.x * ic; oc.y = c.y * ic; oc.z = c.z * ic; oc.w = c.w * ic;
  ((float4*)dirs)[t] = oa;
  ((float4*)dirs)[t + 256] = ob;
  ((float4*)dirs)[t + 512] = oc;
}

__global__ __launch_bounds__(256) void cast_w_kernel(
    const float* __restrict__ W, bf16_t* __restrict__ Wb) {
  const int i = blockIdx.x * 256 + threadIdx.x;
  const float4 v = ((const float4*)W)[i];
  union { bf16_t b[4]; uint2 u; } pk;
  pk.b[0] = (bf16_t)v.x; pk.b[1] = (bf16_t)v.y;
  pk.b[2] = (bf16_t)v.z; pk.b[3] = (bf16_t)v.w;
  ((uint2*)Wb)[i] = pk.u;
}

extern "C" void kernel_launch(void* const* d_in, const int* in_sizes, int n_in,
                              void* d_out, int out_size, void* d_ws,
                              size_t ws_size, hipStream_t stream) {
  const float* h0 = (const float*)d_in[0];
  const float* W1 = (const float*)d_in[1];
  const float* b1 = (const float*)d_in[2];
  const float* W2 = (const float*)d_in[3];
  const float* b2 = (const float*)d_in[4];
  const float* ae = (const float*)d_in[5];
  const float* ac = (const float*)d_in[6];
  const float* an = (const float*)d_in[7];
  float* outF = (float*)d_out;

  char* ws = (char*)d_ws;
  bf16_t* hb = (bf16_t*)ws;  ws += (size_t)BATCH * DIM * 2;   // 32 MB
  bf16_t* Tb = (bf16_t*)ws;  ws += (size_t)BATCH * DIM * 2;   // 32 MB
  bf16_t* W1b = (bf16_t*)ws; ws += (size_t)DIM * DIM * 2;     // 2 MB
  bf16_t* W2b = (bf16_t*)ws; ws += (size_t)DIM * DIM * 2;     // 2 MB
  float* dirs = (float*)ws;  ws += 3 * DIM * 4;
  f32x4* coef = (f32x4*)ws;  ws += (size_t)BATCH * 16;
  float* scaleArr = (float*)ws; ws += (size_t)BATCH * 4;

  prep_dirs<<<1, 256, 0, stream>>>(ae, ac, an, dirs);
  cast_w_kernel<<<DIM * DIM / 1024, 256, 0, stream>>>(W1, W1b);
  cast_w_kernel<<<DIM * DIM / 1024, 256, 0, stream>>>(W2, W2b);
  // layer-0 stats from fp32 h0 (no clamp) + cast h0 -> hb
  stats_kernel<1><<<BATCH, 256, 0, stream>>>(h0, hb, scaleArr, coef, dirs, 0);

  dim3 grid(BATCH / 128, DIM / 128);
  for (int l = 0; l < NLAYER; ++l) {
    gemm_kernel<0><<<grid, 256, 0, stream>>>(hb, W1b, b1, Tb, nullptr, nullptr,
                                             nullptr, scaleArr, nullptr);
    if (l < NLAYER - 1) {
      gemm_kernel<1><<<grid, 256, 0, stream>>>(Tb, W2b, b2, hb, nullptr, coef,
                                               dirs, nullptr, hb);
      stats_kernel<0><<<BATCH, 256, 0, stream>>>(hb, nullptr, scaleArr, coef,
                                                 dirs, 1);
    } else {
      gemm_kernel<2><<<grid, 256, 0, stream>>>(Tb, W2b, b2, nullptr, outF, coef,
                                               dirs, nullptr, hb);
      // final stats read the fp32 result directly (no hb write in MODE 2)
      stats_kernel<1><<<BATCH, 256, 0, stream>>>(outF, nullptr, scaleArr, coef,
                                                 dirs, 1);
      finalize_kernel<<<BATCH, 256, 0, stream>>>(outF, scaleArr);
    }
  }
}